// Round 6
// baseline (186.319 us; speedup 1.0000x reference)
//
#include <hip/hip_runtime.h>
#include <hip/hip_bf16.h>

// ---------- types ----------
typedef __attribute__((ext_vector_type(8))) short s16x8;
typedef __attribute__((ext_vector_type(4))) short s16x4;
typedef __attribute__((ext_vector_type(4))) float f32x4;

__device__ __forceinline__ float b2f(short s) {
  return __uint_as_float(((unsigned)(unsigned short)s) << 16);
}
__device__ __forceinline__ short f2b(float f) {
  unsigned u = __float_as_uint(f);
  unsigned r = u + 0x7fffu + ((u >> 16) & 1u);   // round-to-nearest-even
  return (short)(r >> 16);
}

// async global->LDS, 16B per lane; LDS dest = wave-uniform base + lane*16
__device__ __forceinline__ void gload16(const short* g, short* l) {
  __builtin_amdgcn_global_load_lds((const __attribute__((address_space(1))) void*)g,
                                   (__attribute__((address_space(3))) void*)l, 16, 0, 0);
}

// ---------- problem constants ----------
#define BATCH 64
#define NP    196
#define TL    77
#define DM    512
#define CIMG  1024

// ---------- prep: weight transposes/casts + txt cast + img transpose
//            + zero partials + folded Q bias ----------
// grid dim3(32,16,73), 256 threads
// z=0: Wi f32[1024][512] -> wiB bf16 (straight cast)
// z=1..5: Wt,Wq,Wk,Wv,Wo -> transposed bf16
// z=6..69: img transpose (b = z-6)
// z=70,71: txt cast
// z=72: zero partA||partC; block(31,15) computes biasQ = bq + bi@Wq
__global__ __launch_bounds__(256)
void prep_kernel(const float* __restrict__ Wi, const float* __restrict__ Wt,
                 const float* __restrict__ Wq, const float* __restrict__ Wk,
                 const float* __restrict__ Wv, const float* __restrict__ Wo,
                 short* __restrict__ wiB, short* __restrict__ WtT,
                 short* __restrict__ WqT, short* __restrict__ WkT,
                 short* __restrict__ WvT, short* __restrict__ WoT,
                 const float* __restrict__ txt, short* __restrict__ textB,
                 const float* __restrict__ img, short* __restrict__ aimg,
                 float* __restrict__ partZero,
                 const float* __restrict__ bi, const float* __restrict__ bq,
                 float* __restrict__ biasQ) {
  int z = blockIdx.z;
  __shared__ float tile[32][33];
  int tx = threadIdx.x & 31, ty = threadIdx.x >> 5;   // ty 0..7
  if (z == 0) {
    // Wi straight cast: 131072 float4s over 512 blocks x 256 threads
    int gid = (blockIdx.y * 32 + blockIdx.x) * 256 + threadIdx.x;
    float4 v = ((const float4*)Wi)[gid];
    s16x4 o;
    o[0] = f2b(v.x); o[1] = f2b(v.y); o[2] = f2b(v.z); o[3] = f2b(v.w);
    ((s16x4*)wiB)[gid] = o;
    return;
  }
  if (z < 6) {
    const float* W; short* WT; int K;
    switch (z) {
      case 1: W = Wt; WT = WtT; K = 1024; break;
      case 2: W = Wq; WT = WqT; K = 512;  break;
      case 3: W = Wk; WT = WkT; K = 512;  break;
      case 4: W = Wv; WT = WvT; K = 512;  break;
      default: W = Wo; WT = WoT; K = 512; break;
    }
    int k0 = blockIdx.x * 32, n0 = blockIdx.y * 32;
    if (k0 >= K) return;
    #pragma unroll
    for (int i = 0; i < 4; i++)
      tile[ty + i * 8][tx] = W[(size_t)(k0 + ty + i * 8) * 512 + n0 + tx];
    __syncthreads();
    #pragma unroll
    for (int i = 0; i < 4; i++)
      WT[(size_t)(n0 + ty + i * 8) * K + k0 + tx] = f2b(tile[tx][ty + i * 8]);
    return;
  }
  if (z < 70) {
    if (blockIdx.y >= 7) return;
    int b = z - 6;
    int c0 = blockIdx.x * 32, n0 = blockIdx.y * 32;
    const float* ib = img + (size_t)b * CIMG * NP;
    #pragma unroll
    for (int i = 0; i < 4; i++) {
      int n = n0 + tx;
      tile[ty + i * 8][tx] = (n < NP) ? ib[(size_t)(c0 + ty + i * 8) * NP + n] : 0.f;
    }
    __syncthreads();
    short* ob = aimg + (size_t)b * NP * CIMG;
    #pragma unroll
    for (int i = 0; i < 4; i++) {
      int n = n0 + ty + i * 8;
      if (n < NP) ob[(size_t)n * CIMG + c0 + tx] = f2b(tile[tx][ty + i * 8]);
    }
    return;
  }
  if (z < 72) {
    int fb = (z - 70) * 512 + blockIdx.y * 32 + blockIdx.x;
    int n4 = (int)((size_t)BATCH * TL * 1024 / 4);
    for (int i = fb * 256 + threadIdx.x; i < n4; i += 1024 * 256) {
      float4 v = ((const float4*)txt)[i];
      s16x4 o;
      o[0] = f2b(v.x); o[1] = f2b(v.y); o[2] = f2b(v.z); o[3] = f2b(v.w);
      ((s16x4*)textB)[i] = o;
    }
    return;
  }
  // z == 72
  int id = (blockIdx.y * 32 + blockIdx.x) * 256 + threadIdx.x;
  if (id < 16384) ((float4*)partZero)[id] = make_float4(0.f, 0.f, 0.f, 0.f);
  if (blockIdx.x == 31 && blockIdx.y == 15) {
    int d0 = threadIdx.x * 2;
    float a0 = bq[d0], a1 = bq[d0 + 1];
    for (int e = 0; e < 512; e++) {
      float bie = bi[e];
      a0 += bie * Wq[(size_t)e * 512 + d0];
      a1 += bie * Wq[(size_t)e * 512 + d0 + 1];
    }
    biasQ[d0] = a0; biasQ[d0 + 1] = a1;
  }
}

// ---------- MFMA GEMM core: C[M,N] = A[M,K](bf16) x BT[N,K]^T + bias ----------
// BM=64, BN=128, BK=64, 4 waves. Depth-2 counted-vmcnt pipeline: vmcnt never
// drains to 0 in the loop (T4). XOR-swizzled LDS (linear dest + inverse-
// swizzled global src col + swizzled read). Requires M%64==0,N%128==0,K%128==0.
__device__ __forceinline__ void gemm_core(
    short (*As)[64 * 64], short (*Bs)[128 * 64], float (*pc)[128],
    const short* __restrict__ A, const short* __restrict__ BT,
    const float* __restrict__ bias, const float* __restrict__ bias2,
    float* __restrict__ outF, short* __restrict__ outB,
    float* __restrict__ part, int rowsPerB,
    int bm, int bn, int M, int K, int N) {
  int tid = threadIdx.x, wave = tid >> 6, lane = tid & 63;
  int r = lane & 15, kg = lane >> 4, rr7 = r & 7;
  int wr = (wave >> 1) * 32, wc = (wave & 1) * 64;
  int l8 = lane >> 3, g8 = lane & 7;
  int scol = ((g8 ^ l8) << 3);          // swizzled source k-offset (elems)
  const short* gA = A + (size_t)(bm + wave * 16 + l8) * K + scol;
  const short* gB = BT + (size_t)(bn + wave * 32 + l8) * K + scol;

  f32x4 acc[2][4];
  #pragma unroll
  for (int i = 0; i < 2; i++)
    #pragma unroll
    for (int j = 0; j < 4; j++) acc[i][j] = (f32x4){0.f, 0.f, 0.f, 0.f};

  auto stage = [&](int buf, int k0) {   // 6 global_load_lds per wave
    #pragma unroll
    for (int j = 0; j < 2; j++)
      gload16(gA + (size_t)(j * 8) * K + k0, &As[buf][(wave * 16 + j * 8) * 64]);
    #pragma unroll
    for (int j = 0; j < 4; j++)
      gload16(gB + (size_t)(j * 8) * K + k0, &Bs[buf][(wave * 32 + j * 8) * 64]);
  };
  auto compute = [&](int buf) {
    s16x8 af[2][2], bf[4][2];
    #pragma unroll
    for (int ks = 0; ks < 2; ks++) {
      int gsw = (((ks << 2) + kg) ^ rr7) << 3;   // swizzled granule (elems)
      #pragma unroll
      for (int i = 0; i < 2; i++)
        af[i][ks] = *(const s16x8*)&As[buf][(wr + i * 16 + r) * 64 + gsw];
      #pragma unroll
      for (int j = 0; j < 4; j++)
        bf[j][ks] = *(const s16x8*)&Bs[buf][(wc + j * 16 + r) * 64 + gsw];
    }
    #pragma unroll
    for (int ks = 0; ks < 2; ks++)
      #pragma unroll
      for (int i = 0; i < 2; i++)
        #pragma unroll
        for (int j = 0; j < 4; j++)
          acc[i][j] = __builtin_amdgcn_mfma_f32_16x16x32_bf16(af[i][ks], bf[j][ks], acc[i][j], 0, 0, 0);
  };

  if (part) pc[tid >> 7][tid & 127] = 0.f;
  // prologue: 2 tiles in flight (12 loads/wave)
  stage(0, 0);
  stage(1, 64);
  int nt = K >> 6;
  for (int t = 0; t < nt; t++) {
    // wait for tile t only (tile t+1 stays in flight), then barrier so ALL
    // waves' quarters of tile t are in LDS (vmcnt BEFORE barrier).
    if (t + 1 < nt) asm volatile("s_waitcnt vmcnt(6)" ::: "memory");
    else            asm volatile("s_waitcnt vmcnt(0)" ::: "memory");
    __builtin_amdgcn_s_barrier();
    asm volatile("" ::: "memory");
    compute(t & 1);
    if (t + 2 < nt) {
      asm volatile("" ::: "memory");
      __builtin_amdgcn_s_barrier();      // all waves done READING buf[t&1]
      asm volatile("" ::: "memory");
      stage(t & 1, (t + 2) << 6);        // overwrite with tile t+2
    }
  }

  // epilogue: C/D layout col=lane&15, row=(lane>>4)*4+reg
  int bnd = part ? (bm / rowsPerB + 1) * rowsPerB : 0x7fffffff;
  #pragma unroll
  for (int i = 0; i < 2; i++) {
    float ps[4][2] = {{0.f, 0.f}, {0.f, 0.f}, {0.f, 0.f}, {0.f, 0.f}};
    #pragma unroll
    for (int rr = 0; rr < 4; rr++) {
      int row = bm + wr + i * 16 + kg * 4 + rr;
      int slot = (row >= bnd) ? 1 : 0;
      #pragma unroll
      for (int j = 0; j < 4; j++) {
        int col = bn + wc + j * 16 + r;
        float bval = (col < 512) ? bias[col] : bias2[col - 512];
        float v = acc[i][j][rr] + bval;
        if (outF) outF[(size_t)row * N + col] = v;
        if (outB) outB[(size_t)row * N + col] = f2b(v);
        ps[j][slot] += v;
      }
    }
    if (part) {
      #pragma unroll
      for (int j = 0; j < 4; j++) {
        atomicAdd(&pc[0][wc + j * 16 + r], ps[j][0]);
        if (ps[j][1] != 0.f) atomicAdd(&pc[1][wc + j * 16 + r], ps[j][1]);
      }
    }
  }
  if (part) {
    __syncthreads();
    int slot = tid >> 7, c = tid & 127;
    int b = bm / rowsPerB + slot;
    bool valid = (slot == 0) || (bnd <= bm + 63);
    if (valid && b < M / rowsPerB)
      atomicAdd(&part[(size_t)b * 512 + bn + c], pc[slot][c]);
  }
}

// 1-D grid; bijective XCD-chunked linearization (m204), y-fast within chunk so
// blocks sharing A-stripes AND B-stripes are contiguous on one XCD's L2.
__global__ __launch_bounds__(256)
void gemm_one(const short* __restrict__ A, const short* __restrict__ BT,
              const float* __restrict__ bias, const float* __restrict__ bias2,
              float* __restrict__ outF, short* __restrict__ outB,
              float* __restrict__ part, int rowsPerB,
              int M, int K, int N, int lny) {
  __shared__ __align__(16) short As[2][64 * 64];
  __shared__ __align__(16) short Bs[2][128 * 64];
  __shared__ float pc[2][128];
  int nwg = gridDim.x, orig = blockIdx.x;
  int q8 = nwg >> 3, rm = nwg & 7;
  int xcd = orig & 7, idx = orig >> 3;
  int lin = (xcd < rm ? xcd * (q8 + 1) : rm * (q8 + 1) + (xcd - rm) * q8) + idx;
  int bx = lin >> lny, by = lin & ((1 << lny) - 1);
  gemm_core(As, Bs, pc, A, BT, bias, bias2, outF, outB, part, rowsPerB,
            bx * 64, by * 128, M, K, N);
}

// ---------- MFMA attention: one block per (b,h), 4 waves ----------
// kvB layout: [B*TL][1024] bf16, cols 0..511 = k, 512..1023 = v
// wAll layout: [bh][196][80] bf16 (cols 77..79 junk-zero)
__global__ __launch_bounds__(256)
void attn_kernel(const short* __restrict__ qB, const short* __restrict__ kvB,
                 short* __restrict__ attnB, short* __restrict__ wAll) {
  __shared__ short kls[80 * 72];        // K rows padded to 80, stride 72 (2-way)
  __shared__ short vtls[64 * 104];      // V^T [d][t], t<96 used, stride 104 (2-way)
  __shared__ short pls[4][16 * 104];    // per-wave P tile [16 rows][t]
  int bh = blockIdx.x, b = bh >> 3, h = bh & 7;
  int tid = threadIdx.x, wave = tid >> 6, lane = tid & 63;
  int r = lane & 15, kg = lane >> 4;

  for (int i = lane; i < 208; i += 64)
    *(s16x8*)&pls[wave][i * 8] = (s16x8){0, 0, 0, 0, 0, 0, 0, 0};

  for (int idx = tid; idx < 80 * 8; idx += 256) {
    int t = idx >> 3, c8 = (idx & 7) << 3;
    s16x8 v = (s16x8){0, 0, 0, 0, 0, 0, 0, 0};
    if (t < 77) v = *(const s16x8*)&kvB[((size_t)(b * TL + t)) * 1024 + h * 64 + c8];
    *(s16x8*)&kls[t * 72 + c8] = v;
  }
  for (int idx = tid; idx < 64 * 12; idx += 256) {
    int d = idx & 63, t8 = idx >> 6;    // t8 0..11 covers t<96
    s16x8 v;
    #pragma unroll
    for (int j = 0; j < 8; j++) {
      int t = t8 * 8 + j;
      v[j] = (t < 77) ? kvB[((size_t)(b * TL + t)) * 1024 + 512 + h * 64 + d] : (short)0;
    }
    *(s16x8*)&vtls[d * 104 + t8 * 8] = v;
  }
  __syncthreads();

  s16x8 vf[4][3];
  #pragma unroll
  for (int jd = 0; jd < 4; jd++)
    #pragma unroll
    for (int kk = 0; kk < 3; kk++)
      vf[jd][kk] = *(const s16x8*)&vtls[(jd * 16 + r) * 104 + kg * 8 + kk * 32];

  for (int mf = wave; mf < 13; mf += 4) {
    int m0 = mf * 16;
    int qrow = m0 + r; if (qrow > 195) qrow = 195;
    const short* qp = qB + ((size_t)(b * NP + qrow)) * 512 + h * 64 + kg * 8;
    s16x8 qf0 = *(const s16x8*)qp;
    s16x8 qf1 = *(const s16x8*)(qp + 32);

    f32x4 s[5];
    #pragma unroll
    for (int j = 0; j < 5; j++) s[j] = (f32x4){0.f, 0.f, 0.f, 0.f};
    __builtin_amdgcn_s_setprio(1);
    #pragma unroll
    for (int j = 0; j < 5; j++) {
      s16x8 kf0 = *(const s16x8*)&kls[(j * 16 + r) * 72 + kg * 8];
      s16x8 kf1 = *(const s16x8*)&kls[(j * 16 + r) * 72 + kg * 8 + 32];
      s[j] = __builtin_amdgcn_mfma_f32_16x16x32_bf16(qf0, kf0, s[j], 0, 0, 0);
      s[j] = __builtin_amdgcn_mfma_f32_16x16x32_bf16(qf1, kf1, s[j], 0, 0, 0);
    }
    __builtin_amdgcn_s_setprio(0);
    float st[5][4];
    float mx[4] = {-3e38f, -3e38f, -3e38f, -3e38f};
    #pragma unroll
    for (int j = 0; j < 5; j++) {
      bool valid = (j * 16 + r) < 77;
      #pragma unroll
      for (int rr = 0; rr < 4; rr++) {
        float v = valid ? s[j][rr] * 0.125f : -3e38f;
        st[j][rr] = v;
        mx[rr] = fmaxf(mx[rr], v);
      }
    }
    #pragma unroll
    for (int m = 1; m < 16; m <<= 1)
      #pragma unroll
      for (int rr = 0; rr < 4; rr++)
        mx[rr] = fmaxf(mx[rr], __shfl_xor(mx[rr], m, 64));
    float sm[4] = {0.f, 0.f, 0.f, 0.f};
    #pragma unroll
    for (int j = 0; j < 5; j++)
      #pragma unroll
      for (int rr = 0; rr < 4; rr++) {
        float e = __expf(st[j][rr] - mx[rr]);
        st[j][rr] = e;
        sm[rr] += e;
      }
    #pragma unroll
    for (int m = 1; m < 16; m <<= 1)
      #pragma unroll
      for (int rr = 0; rr < 4; rr++)
        sm[rr] += __shfl_xor(sm[rr], m, 64);
    float rinv[4];
    #pragma unroll
    for (int rr = 0; rr < 4; rr++) rinv[rr] = 1.f / sm[rr];

    #pragma unroll
    for (int j = 0; j < 5; j++) {
      int t = j * 16 + r;
      #pragma unroll
      for (int rr = 0; rr < 4; rr++)
        pls[wave][(kg * 4 + rr) * 104 + t] = f2b(st[j][rr] * rinv[rr]);
    }
    asm volatile("s_waitcnt lgkmcnt(0)" ::: "memory");
    __builtin_amdgcn_sched_barrier(0);

    // vectorized wAll store: 16 rows x 10 chunks of 8 shorts (stride 80)
    #pragma unroll
    for (int i2 = 0; i2 < 3; i2++) {
      int cid = lane + i2 * 64;
      if (cid < 160) {
        int row = cid / 10, cc = cid - row * 10;
        int grow = m0 + row;
        if (grow < 196)
          *(s16x8*)&wAll[((size_t)bh * 196 + grow) * 80 + cc * 8] =
              *(const s16x8*)&pls[wave][row * 104 + cc * 8];
      }
    }

    s16x8 pf[3];
    #pragma unroll
    for (int kk = 0; kk < 3; kk++)
      pf[kk] = *(const s16x8*)&pls[wave][r * 104 + kg * 8 + kk * 32];
    f32x4 o[4];
    #pragma unroll
    for (int jd = 0; jd < 4; jd++) o[jd] = (f32x4){0.f, 0.f, 0.f, 0.f};
    __builtin_amdgcn_s_setprio(1);
    #pragma unroll
    for (int kk = 0; kk < 3; kk++)
      #pragma unroll
      for (int jd = 0; jd < 4; jd++)
        o[jd] = __builtin_amdgcn_mfma_f32_16x16x32_bf16(pf[kk], vf[jd][kk], o[jd], 0, 0, 0);
    __builtin_amdgcn_s_setprio(0);
    #pragma unroll
    for (int jd = 0; jd < 4; jd++)
      #pragma unroll
      for (int rr = 0; rr < 4; rr++) {
        int row = m0 + kg * 4 + rr;
        if (row < 196)
          attnB[((size_t)(b * NP + row)) * 512 + h * 64 + jd * 16 + r] = f2b(o[jd][rr]);
      }
  }
}

// ---------- mean over heads of attention weights (wAll stride 80) ----------
__global__ void meanw_kernel(const short* __restrict__ w_all, float* __restrict__ outW) {
  int i = blockIdx.x * 256 + threadIdx.x;
  if (i >= BATCH * NP * TL) return;
  int b = i / (NP * TL);
  int rm = i - b * (NP * TL);
  int n = rm / 77, t = rm - n * 77;
  float s = 0.f;
  #pragma unroll
  for (int h = 0; h < 8; h++)
    s += b2f(w_all[(((size_t)(b * 8 + h)) * 196 + n) * 80 + t]);
  outW[i] = s * 0.125f;
}

// ---------- finalize means + l2 normalize (partials include bias) ----------
__global__ __launch_bounds__(256)
void avg_final(const float* __restrict__ partA, const float* __restrict__ partC,
               float* __restrict__ oAvg, float* __restrict__ oCls,
               float* __restrict__ normA, float* __restrict__ normC) {
  int b = blockIdx.x;
  int c0 = threadIdx.x * 2;
  float a0 = partA[(size_t)b * 512 + c0] * (1.f / 196.f);
  float a1 = partA[(size_t)b * 512 + c0 + 1] * (1.f / 196.f);
  float t0 = partC[(size_t)b * 512 + c0] * (1.f / 77.f);
  float t1 = partC[(size_t)b * 512 + c0 + 1] * (1.f / 77.f);
  float sqA = a0 * a0 + a1 * a1, sqC = t0 * t0 + t1 * t1;
  #pragma unroll
  for (int off = 32; off > 0; off >>= 1) {
    sqA += __shfl_down(sqA, off, 64);
    sqC += __shfl_down(sqC, off, 64);
  }
  __shared__ float redA[4], redC[4];
  __shared__ float rAs, rCs;
  int wv = threadIdx.x >> 6, ln = threadIdx.x & 63;
  if (ln == 0) { redA[wv] = sqA; redC[wv] = sqC; }
  __syncthreads();
  if (threadIdx.x == 0) {
    float ta = redA[0] + redA[1] + redA[2] + redA[3];
    float tc = redC[0] + redC[1] + redC[2] + redC[3];
    rAs = 1.f / fmaxf(sqrtf(ta), 1e-8f);
    rCs = 1.f / fmaxf(sqrtf(tc), 1e-8f);
  }
  __syncthreads();
  float rA = rAs, rC = rCs;
  oAvg[(size_t)b * 512 + c0] = a0;       oAvg[(size_t)b * 512 + c0 + 1] = a1;
  oCls[(size_t)b * 512 + c0] = t0;       oCls[(size_t)b * 512 + c0 + 1] = t1;
  normA[(size_t)b * 512 + c0] = a0 * rA; normA[(size_t)b * 512 + c0 + 1] = a1 * rA;
  normC[(size_t)b * 512 + c0] = t0 * rC; normC[(size_t)b * 512 + c0 + 1] = t1 * rC;
}

// ---------- cosine similarity matrix 64x64 ----------
__global__ __launch_bounds__(256)
void score_kernel(const float* __restrict__ normA, const float* __restrict__ normC,
                  float* __restrict__ outScore) {
  int i = blockIdx.x;
  __shared__ float als[DM];
  __shared__ float part[256];
  for (int c = threadIdx.x; c < DM; c += 256) als[c] = normA[(size_t)i * DM + c];
  __syncthreads();
  int j = threadIdx.x & 63;
  int ch = threadIdx.x >> 6;
  float s = 0.f;
  for (int c = ch * 128; c < ch * 128 + 128; c++) s += als[c] * normC[(size_t)j * DM + c];
  part[threadIdx.x] = s;
  __syncthreads();
  if (threadIdx.x < 64) {
    outScore[(size_t)i * 64 + j] = part[j] + part[64 + j] + part[128 + j] + part[192 + j];
  }
}

// ---------- launcher ----------
extern "C" void kernel_launch(void* const* d_in, const int* in_sizes, int n_in,
                              void* d_out, int out_size, void* d_ws, size_t ws_size,
                              hipStream_t stream) {
  (void)in_sizes; (void)n_in; (void)out_size; (void)ws_size;
  const float* img = (const float*)d_in[0];
  const float* txt = (const float*)d_in[1];
  const float* Wi  = (const float*)d_in[2];
  const float* bi  = (const float*)d_in[3];
  const float* Wt  = (const float*)d_in[4];
  const float* bt  = (const float*)d_in[5];
  const float* Wq  = (const float*)d_in[6];
  const float* bq  = (const float*)d_in[7];
  const float* Wk  = (const float*)d_in[8];
  const float* bk  = (const float*)d_in[9];
  const float* Wv  = (const float*)d_in[10];
  const float* bv  = (const float*)d_in[11];
  const float* Wo  = (const float*)d_in[12];
  const float* bo  = (const float*)d_in[13];
  float* out = (float*)d_out;

  constexpr size_t MI = (size_t)BATCH * NP;   // 12544
  constexpr size_t MT = (size_t)BATCH * TL;   // 4928

  // region map — no aliasing (ws is 256 MB, we use ~98 MB)
  constexpr size_t O_AIMG  = 0;                                // 25,690,112
  constexpr size_t O_QBUF  = O_AIMG + MI * 1024 * 2;           // 12,845,056
  constexpr size_t O_ATTNB = O_QBUF + MI * 512 * 2;            // 12,845,056
  constexpr size_t O_TEXTB = O_ATTNB + MI * 512 * 2;           // 10,092,544
  constexpr size_t O_PTXTB = O_TEXTB + MT * 1024 * 2;          //  5,046,272
  constexpr size_t O_KV    = O_PTXTB + MT * 512 * 2;           // 10,092,544
  constexpr size_t O_WTT   = O_KV + MT * 1024 * 2;             //  1 MB
  constexpr size_t O_WQT   = O_WTT + 1024 * 512 * 2;
  constexpr size_t O_WKT   = O_WQT + 512 * 512 * 2;
  constexpr size_t O_WVT   = O_WKT + 512 * 512 * 2;            // contiguous after WKT
  constexpr size_t O_WOT   = O_WVT + 512 * 512 * 2;
  constexpr size_t O_WIB   = O_WOT + 512 * 512 * 2;            // Wi bf16 [1024][512]
  constexpr size_t O_WIWQT = O_WIB + 1024 * 512 * 2;           // (Wi@Wq)^T [512][1024]
  constexpr size_t O_WALL  = O_WIWQT + 512 * 1024 * 2;
  constexpr size_t SZ_WALL = (size_t)BATCH * 8 * 196 * 80 * 2; // 16,056,320
  constexpr size_t O_PART  = O_WALL + SZ_WALL;                 // partA||partC
  constexpr size_t O_BIASQ = O_PART + 262144;

  char* ws = (char*)d_ws;
  short* aimg   = (short*)(ws + O_AIMG);
  short* qBuf   = (short*)(ws + O_QBUF);
  short* attnB  = (short*)(ws + O_ATTNB);
  short* textB  = (short*)(ws + O_TEXTB);
  short* ptxtB  = (short*)(ws + O_PTXTB);
  short* kvBuf  = (short*)(ws + O_KV);
  short* wtt    = (short*)(ws + O_WTT);
  short* wqt    = (short*)(ws + O_WQT);
  short* wkt    = (short*)(ws + O_WKT);
  short* wvt    = (short*)(ws + O_WVT);
  short* wot    = (short*)(ws + O_WOT);
  short* wiB    = (short*)(ws + O_WIB);
  short* wiwqT  = (short*)(ws + O_WIWQT);
  short* wAll   = (short*)(ws + O_WALL);
  float* partA  = (float*)(ws + O_PART);
  float* partC  = (float*)(ws + O_PART + 131072);
  float* biasQ  = (float*)(ws + O_BIASQ);
  float* normA  = (float*)(ws + O_BIASQ + 4096);
  float* normC  = (float*)(ws + O_BIASQ + 4096 + 131072);

  // output layout (floats)
  float* oScore = out;                                    // 64*64
  float* oAttn  = out + 4096;                             // 64*196*512
  float* oW     = oAttn + MI * 512;                       // 64*196*77
  float* oAvg   = oW + (size_t)BATCH * NP * TL;           // 64*512
  float* oCls   = oAvg + (size_t)BATCH * DM;              // 64*512
  float* oPtxt  = oCls + (size_t)BATCH * DM;              // 64*77*512

  prep_kernel<<<dim3(32, 16, 73), 256, 0, stream>>>(
      Wi, Wt, Wq, Wk, Wv, Wo, wiB, wtt, wqt, wkt, wvt, wot,
      txt, textB, img, aimg, partA, bi, bq, biasQ);

  // weight fold: wiwqT[d][c] = sum_e Wq[e][d]*Wi[c][e]  (A=wqt, BT=wiB)
  // bias = partA (zeros at this point in the stream)
  gemm_one<<<dim3(64), 256, 0, stream>>>(wqt, wiB, partA, partA, nullptr, wiwqT,
                                         nullptr, 1 << 30, 512, 512, 1024, 3);
  // proj_txt (fused cls column-sum into partC)
  gemm_one<<<dim3(308), 256, 0, stream>>>(textB, wtt, bt, bt, oPtxt, ptxtB,
                                          partC, 77, (int)MT, 1024, 512, 2);
  // q direct: aimg @ (Wi@Wq) + biasQ   (proj_img eliminated)
  gemm_one<<<dim3(784), 256, 0, stream>>>(aimg, wiwqT, biasQ, biasQ, nullptr, qBuf,
                                          nullptr, 1 << 30, (int)MI, 1024, 512, 2);
  // kv: ptxt @ [Wk | Wv] + [bk | bv]
  gemm_one<<<dim3(616), 256, 0, stream>>>(ptxtB, wkt, bk, bv, nullptr, kvBuf,
                                          nullptr, 1 << 30, (int)MT, 512, 1024, 3);

  attn_kernel<<<dim3(512), 256, 0, stream>>>(qBuf, kvBuf, attnB, wAll);
  meanw_kernel<<<dim3((BATCH * NP * TL + 255) / 256), 256, 0, stream>>>(wAll, oW);

  // attn output projection with fused avg column-sum into partA
  gemm_one<<<dim3(784), 256, 0, stream>>>(attnB, wot, bo, bo, oAttn, nullptr,
                                          partA, 196, (int)MI, 512, 512, 2);

  avg_final<<<dim3(64), 256, 0, stream>>>(partA, partC, oAvg, oCls, normA, normC);
  score_kernel<<<dim3(64), 256, 0, stream>>>(normA, normC, oScore);
}

// Round 7
// 174.219 us; speedup vs baseline: 1.0695x; 1.0695x over previous
//
#include <hip/hip_runtime.h>
#include <hip/hip_bf16.h>

// ---------- types ----------
typedef __attribute__((ext_vector_type(8))) short s16x8;
typedef __attribute__((ext_vector_type(4))) short s16x4;
typedef __attribute__((ext_vector_type(4))) float f32x4;

__device__ __forceinline__ float b2f(short s) {
  return __uint_as_float(((unsigned)(unsigned short)s) << 16);
}
__device__ __forceinline__ short f2b(float f) {
  unsigned u = __float_as_uint(f);
  unsigned r = u + 0x7fffu + ((u >> 16) & 1u);   // round-to-nearest-even
  return (short)(r >> 16);
}

// async global->LDS, 16B per lane; LDS dest = wave-uniform base + lane*16
__device__ __forceinline__ void gload16(const short* g, short* l) {
  __builtin_amdgcn_global_load_lds((const __attribute__((address_space(1))) void*)g,
                                   (__attribute__((address_space(3))) void*)l, 16, 0, 0);
}

// ---------- problem constants ----------
#define BATCH 64
#define NP    196
#define TL    77
#define DM    512
#define CIMG  1024

// ---------- prep: weight transposes/casts + txt cast + img transpose
//            + zero partials + biasQ partials ----------
// grid dim3(32,16,73), 256 threads
// z=0: Wi f32[1024][512] -> wiB bf16 (straight cast)
// z=1..5: Wt,Wq,Wk,Wv,Wo -> transposed bf16
// z=6..69: img transpose (b=z-6), 64x64 tiles, x<16,y<4
// z=70,71: txt cast
// z=72: y<2: zero partA||partC ; y==2,x<16: biasQ e-slice partials
__global__ __launch_bounds__(256)
void prep_kernel(const float* __restrict__ Wi, const float* __restrict__ Wt,
                 const float* __restrict__ Wq, const float* __restrict__ Wk,
                 const float* __restrict__ Wv, const float* __restrict__ Wo,
                 short* __restrict__ wiB, short* __restrict__ WtT,
                 short* __restrict__ WqT, short* __restrict__ WkT,
                 short* __restrict__ WvT, short* __restrict__ WoT,
                 const float* __restrict__ txt, short* __restrict__ textB,
                 const float* __restrict__ img, short* __restrict__ aimg,
                 float* __restrict__ partZero,
                 const float* __restrict__ bi, float* __restrict__ bqPart) {
  int z = blockIdx.z;
  __shared__ float raw[64 * 65];        // overlaid: 32x33 (weights) / 64x65 (img)
  int tid = threadIdx.x;
  if (z == 0) {
    // Wi straight cast: 131072 float4s over 512 blocks x 256 threads
    int gid = (blockIdx.y * 32 + blockIdx.x) * 256 + tid;
    float4 v = ((const float4*)Wi)[gid];
    s16x4 o;
    o[0] = f2b(v.x); o[1] = f2b(v.y); o[2] = f2b(v.z); o[3] = f2b(v.w);
    ((s16x4*)wiB)[gid] = o;
    return;
  }
  if (z < 6) {
    const float* W; short* WT; int K;
    switch (z) {
      case 1: W = Wt; WT = WtT; K = 1024; break;
      case 2: W = Wq; WT = WqT; K = 512;  break;
      case 3: W = Wk; WT = WkT; K = 512;  break;
      case 4: W = Wv; WT = WvT; K = 512;  break;
      default: W = Wo; WT = WoT; K = 512; break;
    }
    int k0 = blockIdx.x * 32, n0 = blockIdx.y * 32;
    if (k0 >= K) return;
    int tx = tid & 31, ty = tid >> 5;   // ty 0..7
    #pragma unroll
    for (int i = 0; i < 4; i++)
      raw[(ty + i * 8) * 33 + tx] = W[(size_t)(k0 + ty + i * 8) * 512 + n0 + tx];
    __syncthreads();
    #pragma unroll
    for (int i = 0; i < 4; i++)
      WT[(size_t)(n0 + ty + i * 8) * K + k0 + tx] = f2b(raw[tx * 33 + ty + i * 8]);
    return;
  }
  if (z < 70) {
    // img transpose [1024][196] f32 -> [196][1024] bf16, 64x64 tile
    if (blockIdx.x >= 16 || blockIdx.y >= 4) return;
    int b = z - 6;
    int c0 = blockIdx.x * 64, n0 = blockIdx.y * 64;
    const float* ib = img + (size_t)b * CIMG * NP;
    int tx = tid & 15, ty = tid >> 4;   // tx: n-quad, ty: c-row base (0..15)
    int n4 = n0 + tx * 4;
    #pragma unroll
    for (int i = 0; i < 4; i++) {
      int cl = ty + i * 16;
      float4 v = (n4 < NP) ? *(const float4*)&ib[(size_t)(c0 + cl) * NP + n4]
                           : make_float4(0.f, 0.f, 0.f, 0.f);
      raw[cl * 65 + tx * 4 + 0] = v.x;
      raw[cl * 65 + tx * 4 + 1] = v.y;
      raw[cl * 65 + tx * 4 + 2] = v.z;
      raw[cl * 65 + tx * 4 + 3] = v.w;
    }
    __syncthreads();
    short* ob = aimg + (size_t)b * NP * CIMG;
    int nl = tid >> 3, cl0 = (tid & 7) * 8;
    #pragma unroll
    for (int j = 0; j < 2; j++) {
      int n = n0 + nl + j * 32;
      if (n < NP) {
        s16x8 o;
        #pragma unroll
        for (int q = 0; q < 8; q++) o[q] = f2b(raw[(cl0 + q) * 65 + nl + j * 32]);
        *(s16x8*)&ob[(size_t)n * CIMG + c0 + cl0] = o;
      }
    }
    return;
  }
  if (z < 72) {
    int fb = (z - 70) * 512 + blockIdx.y * 32 + blockIdx.x;
    int n4 = (int)((size_t)BATCH * TL * 1024 / 4);
    for (int i = fb * 256 + tid; i < n4; i += 1024 * 256) {
      float4 v = ((const float4*)txt)[i];
      s16x4 o;
      o[0] = f2b(v.x); o[1] = f2b(v.y); o[2] = f2b(v.z); o[3] = f2b(v.w);
      ((s16x4*)textB)[i] = o;
    }
    return;
  }
  // z == 72
  if (blockIdx.y < 2) {
    int id = (blockIdx.y * 32 + blockIdx.x) * 256 + tid;   // exactly [0,16384)
    ((float4*)partZero)[id] = make_float4(0.f, 0.f, 0.f, 0.f);
    return;
  }
  if (blockIdx.y == 2 && blockIdx.x < 16) {
    // biasQ partial: slice s covers e in [s*32, s*32+32)
    int s = blockIdx.x, d0 = tid * 2;
    float a0 = 0.f, a1 = 0.f;
    #pragma unroll
    for (int i = 0; i < 32; i++) {
      int e = s * 32 + i;
      float bie = bi[e];
      a0 += bie * Wq[(size_t)e * 512 + d0];
      a1 += bie * Wq[(size_t)e * 512 + d0 + 1];
    }
    bqPart[s * 512 + d0] = a0;
    bqPart[s * 512 + d0 + 1] = a1;
  }
}

// ---------- MFMA GEMM core: C[M,N] = A[M,K](bf16) x BT[N,K]^T + bias ----------
// BM=64, BN=128, BK=64, 4 waves. Depth-2 counted-vmcnt pipeline: vmcnt never
// drains to 0 in the loop (T4). XOR-swizzled LDS (linear dest + inverse-
// swizzled global src col + swizzled read). Requires M%64==0,N%128==0,K%128==0.
__device__ __forceinline__ void gemm_core(
    short (*As)[64 * 64], short (*Bs)[128 * 64], float (*pc)[128],
    const short* __restrict__ A, const short* __restrict__ BT,
    const float* __restrict__ bias, const float* __restrict__ bias2,
    float* __restrict__ outF, short* __restrict__ outB,
    float* __restrict__ part, int rowsPerB,
    int bm, int bn, int M, int K, int N) {
  int tid = threadIdx.x, wave = tid >> 6, lane = tid & 63;
  int r = lane & 15, kg = lane >> 4, rr7 = r & 7;
  int wr = (wave >> 1) * 32, wc = (wave & 1) * 64;
  int l8 = lane >> 3, g8 = lane & 7;
  int scol = ((g8 ^ l8) << 3);          // swizzled source k-offset (elems)
  const short* gA = A + (size_t)(bm + wave * 16 + l8) * K + scol;
  const short* gB = BT + (size_t)(bn + wave * 32 + l8) * K + scol;

  f32x4 acc[2][4];
  #pragma unroll
  for (int i = 0; i < 2; i++)
    #pragma unroll
    for (int j = 0; j < 4; j++) acc[i][j] = (f32x4){0.f, 0.f, 0.f, 0.f};

  auto stage = [&](int buf, int k0) {   // 6 global_load_lds per wave
    #pragma unroll
    for (int j = 0; j < 2; j++)
      gload16(gA + (size_t)(j * 8) * K + k0, &As[buf][(wave * 16 + j * 8) * 64]);
    #pragma unroll
    for (int j = 0; j < 4; j++)
      gload16(gB + (size_t)(j * 8) * K + k0, &Bs[buf][(wave * 32 + j * 8) * 64]);
  };
  auto compute = [&](int buf) {
    s16x8 af[2][2], bf[4][2];
    #pragma unroll
    for (int ks = 0; ks < 2; ks++) {
      int gsw = (((ks << 2) + kg) ^ rr7) << 3;   // swizzled granule (elems)
      #pragma unroll
      for (int i = 0; i < 2; i++)
        af[i][ks] = *(const s16x8*)&As[buf][(wr + i * 16 + r) * 64 + gsw];
      #pragma unroll
      for (int j = 0; j < 4; j++)
        bf[j][ks] = *(const s16x8*)&Bs[buf][(wc + j * 16 + r) * 64 + gsw];
    }
    #pragma unroll
    for (int ks = 0; ks < 2; ks++)
      #pragma unroll
      for (int i = 0; i < 2; i++)
        #pragma unroll
        for (int j = 0; j < 4; j++)
          acc[i][j] = __builtin_amdgcn_mfma_f32_16x16x32_bf16(af[i][ks], bf[j][ks], acc[i][j], 0, 0, 0);
  };

  if (part) pc[tid >> 7][tid & 127] = 0.f;
  // prologue: 2 tiles in flight (12 loads/wave)
  stage(0, 0);
  stage(1, 64);
  int nt = K >> 6;
  for (int t = 0; t < nt; t++) {
    // wait for tile t only (tile t+1 stays in flight), then barrier so ALL
    // waves' quarters of tile t are in LDS (vmcnt BEFORE barrier).
    if (t + 1 < nt) asm volatile("s_waitcnt vmcnt(6)" ::: "memory");
    else            asm volatile("s_waitcnt vmcnt(0)" ::: "memory");
    __builtin_amdgcn_s_barrier();
    asm volatile("" ::: "memory");
    compute(t & 1);
    if (t + 2 < nt) {
      asm volatile("" ::: "memory");
      __builtin_amdgcn_s_barrier();      // all waves done READING buf[t&1]
      asm volatile("" ::: "memory");
      stage(t & 1, (t + 2) << 6);        // overwrite with tile t+2
    }
  }

  // epilogue: C/D layout col=lane&15, row=(lane>>4)*4+reg
  int bnd = part ? (bm / rowsPerB + 1) * rowsPerB : 0x7fffffff;
  #pragma unroll
  for (int i = 0; i < 2; i++) {
    float ps[4][2] = {{0.f, 0.f}, {0.f, 0.f}, {0.f, 0.f}, {0.f, 0.f}};
    #pragma unroll
    for (int rr = 0; rr < 4; rr++) {
      int row = bm + wr + i * 16 + kg * 4 + rr;
      int slot = (row >= bnd) ? 1 : 0;
      #pragma unroll
      for (int j = 0; j < 4; j++) {
        int col = bn + wc + j * 16 + r;
        float bval = (col < 512) ? bias[col] : bias2[col - 512];
        float v = acc[i][j][rr] + bval;
        if (outF) outF[(size_t)row * N + col] = v;
        if (outB) outB[(size_t)row * N + col] = f2b(v);
        ps[j][slot] += v;
      }
    }
    if (part) {
      #pragma unroll
      for (int j = 0; j < 4; j++) {
        atomicAdd(&pc[0][wc + j * 16 + r], ps[j][0]);
        if (ps[j][1] != 0.f) atomicAdd(&pc[1][wc + j * 16 + r], ps[j][1]);
      }
    }
  }
  if (part) {
    __syncthreads();
    int slot = tid >> 7, c = tid & 127;
    int b = bm / rowsPerB + slot;
    bool valid = (slot == 0) || (bnd <= bm + 63);
    if (valid && b < M / rowsPerB)
      atomicAdd(&part[(size_t)b * 512 + bn + c], pc[slot][c]);
  }
}

// 1-D grid; bijective XCD-chunked linearization (m204), y-fast within chunk so
// blocks sharing A-stripes AND B-stripes are contiguous on one XCD's L2.
// Optional: finalize biasQ = bqVec + sum_s bqPart[s][:] (used by the fold GEMM,
// whose consumers run in later launches — no race).
__global__ __launch_bounds__(256)
void gemm_one(const short* __restrict__ A, const short* __restrict__ BT,
              const float* __restrict__ bias, const float* __restrict__ bias2,
              float* __restrict__ outF, short* __restrict__ outB,
              float* __restrict__ part, int rowsPerB,
              int M, int K, int N, int lny,
              const float* __restrict__ bqPart, const float* __restrict__ bqVec,
              float* __restrict__ bqOut) {
  __shared__ __align__(16) short As[2][64 * 64];
  __shared__ __align__(16) short Bs[2][128 * 64];
  __shared__ float pc[2][128];
  int nwg = gridDim.x, orig = blockIdx.x;
  int q8 = nwg >> 3, rm = nwg & 7;
  int xcd = orig & 7, idx = orig >> 3;
  int lin = (xcd < rm ? xcd * (q8 + 1) : rm * (q8 + 1) + (xcd - rm) * q8) + idx;
  if (bqOut && threadIdx.x < 8 && lin * 8 + 7 < 512) {
    int d = lin * 8 + threadIdx.x;
    float a = bqVec[d];
    #pragma unroll
    for (int s = 0; s < 16; s++) a += bqPart[s * 512 + d];
    bqOut[d] = a;
  }
  int bx = lin >> lny, by = lin & ((1 << lny) - 1);
  gemm_core(As, Bs, pc, A, BT, bias, bias2, outF, outB, part, rowsPerB,
            bx * 64, by * 128, M, K, N);
}

// ---------- MFMA attention: one block per (b,h), 4 waves ----------
// kvB layout: [B*TL][1024] bf16, cols 0..511 = k, 512..1023 = v
// wAll layout: [bh][196][80] bf16 (cols 77..79 junk-zero)
__global__ __launch_bounds__(256)
void attn_kernel(const short* __restrict__ qB, const short* __restrict__ kvB,
                 short* __restrict__ attnB, short* __restrict__ wAll) {
  __shared__ short kls[80 * 72];        // K rows padded to 80, stride 72 (2-way)
  __shared__ short vtls[64 * 104];      // V^T [d][t], t<96 used, stride 104 (2-way)
  __shared__ short pls[4][16 * 104];    // per-wave P tile [16 rows][t]
  int bh = blockIdx.x, b = bh >> 3, h = bh & 7;
  int tid = threadIdx.x, wave = tid >> 6, lane = tid & 63;
  int r = lane & 15, kg = lane >> 4;

  for (int i = lane; i < 208; i += 64)
    *(s16x8*)&pls[wave][i * 8] = (s16x8){0, 0, 0, 0, 0, 0, 0, 0};

  for (int idx = tid; idx < 80 * 8; idx += 256) {
    int t = idx >> 3, c8 = (idx & 7) << 3;
    s16x8 v = (s16x8){0, 0, 0, 0, 0, 0, 0, 0};
    if (t < 77) v = *(const s16x8*)&kvB[((size_t)(b * TL + t)) * 1024 + h * 64 + c8];
    *(s16x8*)&kls[t * 72 + c8] = v;
  }
  for (int idx = tid; idx < 64 * 12; idx += 256) {
    int d = idx & 63, t8 = idx >> 6;    // t8 0..11 covers t<96
    s16x8 v;
    #pragma unroll
    for (int j = 0; j < 8; j++) {
      int t = t8 * 8 + j;
      v[j] = (t < 77) ? kvB[((size_t)(b * TL + t)) * 1024 + 512 + h * 64 + d] : (short)0;
    }
    *(s16x8*)&vtls[d * 104 + t8 * 8] = v;
  }
  __syncthreads();

  s16x8 vf[4][3];
  #pragma unroll
  for (int jd = 0; jd < 4; jd++)
    #pragma unroll
    for (int kk = 0; kk < 3; kk++)
      vf[jd][kk] = *(const s16x8*)&vtls[(jd * 16 + r) * 104 + kg * 8 + kk * 32];

  for (int mf = wave; mf < 13; mf += 4) {
    int m0 = mf * 16;
    int qrow = m0 + r; if (qrow > 195) qrow = 195;
    const short* qp = qB + ((size_t)(b * NP + qrow)) * 512 + h * 64 + kg * 8;
    s16x8 qf0 = *(const s16x8*)qp;
    s16x8 qf1 = *(const s16x8*)(qp + 32);

    f32x4 s[5];
    #pragma unroll
    for (int j = 0; j < 5; j++) s[j] = (f32x4){0.f, 0.f, 0.f, 0.f};
    __builtin_amdgcn_s_setprio(1);
    #pragma unroll
    for (int j = 0; j < 5; j++) {
      s16x8 kf0 = *(const s16x8*)&kls[(j * 16 + r) * 72 + kg * 8];
      s16x8 kf1 = *(const s16x8*)&kls[(j * 16 + r) * 72 + kg * 8 + 32];
      s[j] = __builtin_amdgcn_mfma_f32_16x16x32_bf16(qf0, kf0, s[j], 0, 0, 0);
      s[j] = __builtin_amdgcn_mfma_f32_16x16x32_bf16(qf1, kf1, s[j], 0, 0, 0);
    }
    __builtin_amdgcn_s_setprio(0);
    float st[5][4];
    float mx[4] = {-3e38f, -3e38f, -3e38f, -3e38f};
    #pragma unroll
    for (int j = 0; j < 5; j++) {
      bool valid = (j * 16 + r) < 77;
      #pragma unroll
      for (int rr = 0; rr < 4; rr++) {
        float v = valid ? s[j][rr] * 0.125f : -3e38f;
        st[j][rr] = v;
        mx[rr] = fmaxf(mx[rr], v);
      }
    }
    #pragma unroll
    for (int m = 1; m < 16; m <<= 1)
      #pragma unroll
      for (int rr = 0; rr < 4; rr++)
        mx[rr] = fmaxf(mx[rr], __shfl_xor(mx[rr], m, 64));
    float sm[4] = {0.f, 0.f, 0.f, 0.f};
    #pragma unroll
    for (int j = 0; j < 5; j++)
      #pragma unroll
      for (int rr = 0; rr < 4; rr++) {
        float e = __expf(st[j][rr] - mx[rr]);
        st[j][rr] = e;
        sm[rr] += e;
      }
    #pragma unroll
    for (int m = 1; m < 16; m <<= 1)
      #pragma unroll
      for (int rr = 0; rr < 4; rr++)
        sm[rr] += __shfl_xor(sm[rr], m, 64);
    float rinv[4];
    #pragma unroll
    for (int rr = 0; rr < 4; rr++) rinv[rr] = 1.f / sm[rr];

    #pragma unroll
    for (int j = 0; j < 5; j++) {
      int t = j * 16 + r;
      #pragma unroll
      for (int rr = 0; rr < 4; rr++)
        pls[wave][(kg * 4 + rr) * 104 + t] = f2b(st[j][rr] * rinv[rr]);
    }
    asm volatile("s_waitcnt lgkmcnt(0)" ::: "memory");
    __builtin_amdgcn_sched_barrier(0);

    // vectorized wAll store: 16 rows x 10 chunks of 8 shorts (stride 80)
    #pragma unroll
    for (int i2 = 0; i2 < 3; i2++) {
      int cid = lane + i2 * 64;
      if (cid < 160) {
        int row = cid / 10, cc = cid - row * 10;
        int grow = m0 + row;
        if (grow < 196)
          *(s16x8*)&wAll[((size_t)bh * 196 + grow) * 80 + cc * 8] =
              *(const s16x8*)&pls[wave][row * 104 + cc * 8];
      }
    }

    s16x8 pf[3];
    #pragma unroll
    for (int kk = 0; kk < 3; kk++)
      pf[kk] = *(const s16x8*)&pls[wave][r * 104 + kg * 8 + kk * 32];
    f32x4 o[4];
    #pragma unroll
    for (int jd = 0; jd < 4; jd++) o[jd] = (f32x4){0.f, 0.f, 0.f, 0.f};
    __builtin_amdgcn_s_setprio(1);
    #pragma unroll
    for (int kk = 0; kk < 3; kk++)
      #pragma unroll
      for (int jd = 0; jd < 4; jd++)
        o[jd] = __builtin_amdgcn_mfma_f32_16x16x32_bf16(pf[kk], vf[jd][kk], o[jd], 0, 0, 0);
    __builtin_amdgcn_s_setprio(0);
    #pragma unroll
    for (int jd = 0; jd < 4; jd++)
      #pragma unroll
      for (int rr = 0; rr < 4; rr++) {
        int row = m0 + kg * 4 + rr;
        if (row < 196)
          attnB[((size_t)(b * NP + row)) * 512 + h * 64 + jd * 16 + r] = f2b(o[jd][rr]);
      }
  }
}

// ---------- mean over heads of attention weights (wAll stride 80) ----------
__global__ void meanw_kernel(const short* __restrict__ w_all, float* __restrict__ outW) {
  int i = blockIdx.x * 256 + threadIdx.x;
  if (i >= BATCH * NP * TL) return;
  int b = i / (NP * TL);
  int rm = i - b * (NP * TL);
  int n = rm / 77, t = rm - n * 77;
  float s = 0.f;
  #pragma unroll
  for (int h = 0; h < 8; h++)
    s += b2f(w_all[(((size_t)(b * 8 + h)) * 196 + n) * 80 + t]);
  outW[i] = s * 0.125f;
}

// ---------- finalize means + l2 normalize (partials include bias) ----------
__global__ __launch_bounds__(256)
void avg_final(const float* __restrict__ partA, const float* __restrict__ partC,
               float* __restrict__ oAvg, float* __restrict__ oCls,
               float* __restrict__ normA, float* __restrict__ normC) {
  int b = blockIdx.x;
  int c0 = threadIdx.x * 2;
  float a0 = partA[(size_t)b * 512 + c0] * (1.f / 196.f);
  float a1 = partA[(size_t)b * 512 + c0 + 1] * (1.f / 196.f);
  float t0 = partC[(size_t)b * 512 + c0] * (1.f / 77.f);
  float t1 = partC[(size_t)b * 512 + c0 + 1] * (1.f / 77.f);
  float sqA = a0 * a0 + a1 * a1, sqC = t0 * t0 + t1 * t1;
  #pragma unroll
  for (int off = 32; off > 0; off >>= 1) {
    sqA += __shfl_down(sqA, off, 64);
    sqC += __shfl_down(sqC, off, 64);
  }
  __shared__ float redA[4], redC[4];
  __shared__ float rAs, rCs;
  int wv = threadIdx.x >> 6, ln = threadIdx.x & 63;
  if (ln == 0) { redA[wv] = sqA; redC[wv] = sqC; }
  __syncthreads();
  if (threadIdx.x == 0) {
    float ta = redA[0] + redA[1] + redA[2] + redA[3];
    float tc = redC[0] + redC[1] + redC[2] + redC[3];
    rAs = 1.f / fmaxf(sqrtf(ta), 1e-8f);
    rCs = 1.f / fmaxf(sqrtf(tc), 1e-8f);
  }
  __syncthreads();
  float rA = rAs, rC = rCs;
  oAvg[(size_t)b * 512 + c0] = a0;       oAvg[(size_t)b * 512 + c0 + 1] = a1;
  oCls[(size_t)b * 512 + c0] = t0;       oCls[(size_t)b * 512 + c0 + 1] = t1;
  normA[(size_t)b * 512 + c0] = a0 * rA; normA[(size_t)b * 512 + c0 + 1] = a1 * rA;
  normC[(size_t)b * 512 + c0] = t0 * rC; normC[(size_t)b * 512 + c0 + 1] = t1 * rC;
}

// ---------- cosine similarity matrix 64x64 ----------
__global__ __launch_bounds__(256)
void score_kernel(const float* __restrict__ normA, const float* __restrict__ normC,
                  float* __restrict__ outScore) {
  int i = blockIdx.x;
  __shared__ float als[DM];
  __shared__ float part[256];
  for (int c = threadIdx.x; c < DM; c += 256) als[c] = normA[(size_t)i * DM + c];
  __syncthreads();
  int j = threadIdx.x & 63;
  int ch = threadIdx.x >> 6;
  float s = 0.f;
  for (int c = ch * 128; c < ch * 128 + 128; c++) s += als[c] * normC[(size_t)j * DM + c];
  part[threadIdx.x] = s;
  __syncthreads();
  if (threadIdx.x < 64) {
    outScore[(size_t)i * 64 + j] = part[j] + part[64 + j] + part[128 + j] + part[192 + j];
  }
}

// ---------- launcher ----------
extern "C" void kernel_launch(void* const* d_in, const int* in_sizes, int n_in,
                              void* d_out, int out_size, void* d_ws, size_t ws_size,
                              hipStream_t stream) {
  (void)in_sizes; (void)n_in; (void)out_size; (void)ws_size;
  const float* img = (const float*)d_in[0];
  const float* txt = (const float*)d_in[1];
  const float* Wi  = (const float*)d_in[2];
  const float* bi  = (const float*)d_in[3];
  const float* Wt  = (const float*)d_in[4];
  const float* bt  = (const float*)d_in[5];
  const float* Wq  = (const float*)d_in[6];
  const float* bq  = (const float*)d_in[7];
  const float* Wk  = (const float*)d_in[8];
  const float* bk  = (const float*)d_in[9];
  const float* Wv  = (const float*)d_in[10];
  const float* bv  = (const float*)d_in[11];
  const float* Wo  = (const float*)d_in[12];
  const float* bo  = (const float*)d_in[13];
  float* out = (float*)d_out;

  constexpr size_t MI = (size_t)BATCH * NP;   // 12544
  constexpr size_t MT = (size_t)BATCH * TL;   // 4928

  // region map — no aliasing (ws is 256 MB, we use ~98 MB)
  constexpr size_t O_AIMG  = 0;                                // 25,690,112
  constexpr size_t O_QBUF  = O_AIMG + MI * 1024 * 2;           // 12,845,056
  constexpr size_t O_ATTNB = O_QBUF + MI * 512 * 2;            // 12,845,056
  constexpr size_t O_TEXTB = O_ATTNB + MI * 512 * 2;           // 10,092,544
  constexpr size_t O_PTXTB = O_TEXTB + MT * 1024 * 2;          //  5,046,272
  constexpr size_t O_KV    = O_PTXTB + MT * 512 * 2;           // 10,092,544
  constexpr size_t O_WTT   = O_KV + MT * 1024 * 2;             //  1 MB
  constexpr size_t O_WQT   = O_WTT + 1024 * 512 * 2;
  constexpr size_t O_WKT   = O_WQT + 512 * 512 * 2;
  constexpr size_t O_WVT   = O_WKT + 512 * 512 * 2;            // contiguous after WKT
  constexpr size_t O_WOT   = O_WVT + 512 * 512 * 2;
  constexpr size_t O_WIB   = O_WOT + 512 * 512 * 2;            // Wi bf16 [1024][512]
  constexpr size_t O_WIWQT = O_WIB + 1024 * 512 * 2;           // (Wi@Wq)^T [512][1024]
  constexpr size_t O_WALL  = O_WIWQT + 512 * 1024 * 2;
  constexpr size_t SZ_WALL = (size_t)BATCH * 8 * 196 * 80 * 2; // 16,056,320
  constexpr size_t O_PART  = O_WALL + SZ_WALL;                 // partA||partC
  constexpr size_t O_BIASQ = O_PART + 262144;
  constexpr size_t O_BQP   = O_BIASQ + 4096;                   // 16x512 partials
  constexpr size_t O_NORMA = O_BQP + 32768;
  constexpr size_t O_NORMC = O_NORMA + 131072;

  char* ws = (char*)d_ws;
  short* aimg   = (short*)(ws + O_AIMG);
  short* qBuf   = (short*)(ws + O_QBUF);
  short* attnB  = (short*)(ws + O_ATTNB);
  short* textB  = (short*)(ws + O_TEXTB);
  short* ptxtB  = (short*)(ws + O_PTXTB);
  short* kvBuf  = (short*)(ws + O_KV);
  short* wtt    = (short*)(ws + O_WTT);
  short* wqt    = (short*)(ws + O_WQT);
  short* wkt    = (short*)(ws + O_WKT);
  short* wvt    = (short*)(ws + O_WVT);
  short* wot    = (short*)(ws + O_WOT);
  short* wiB    = (short*)(ws + O_WIB);
  short* wiwqT  = (short*)(ws + O_WIWQT);
  short* wAll   = (short*)(ws + O_WALL);
  float* partA  = (float*)(ws + O_PART);
  float* partC  = (float*)(ws + O_PART + 131072);
  float* biasQ  = (float*)(ws + O_BIASQ);
  float* bqPart = (float*)(ws + O_BQP);
  float* normA  = (float*)(ws + O_NORMA);
  float* normC  = (float*)(ws + O_NORMC);

  // output layout (floats)
  float* oScore = out;                                    // 64*64
  float* oAttn  = out + 4096;                             // 64*196*512
  float* oW     = oAttn + MI * 512;                       // 64*196*77
  float* oAvg   = oW + (size_t)BATCH * NP * TL;           // 64*512
  float* oCls   = oAvg + (size_t)BATCH * DM;              // 64*512
  float* oPtxt  = oCls + (size_t)BATCH * DM;              // 64*77*512

  prep_kernel<<<dim3(32, 16, 73), 256, 0, stream>>>(
      Wi, Wt, Wq, Wk, Wv, Wo, wiB, wtt, wqt, wkt, wvt, wot,
      txt, textB, img, aimg, partA, bi, bqPart);

  // weight fold: wiwqT[d][c] = sum_e Wq[e][d]*Wi[c][e]; also finalizes biasQ
  gemm_one<<<dim3(64), 256, 0, stream>>>(wqt, wiB, partA, partA, nullptr, wiwqT,
                                         nullptr, 1 << 30, 512, 512, 1024, 3,
                                         bqPart, bq, biasQ);
  // proj_txt (fused cls column-sum into partC)
  gemm_one<<<dim3(308), 256, 0, stream>>>(textB, wtt, bt, bt, oPtxt, ptxtB,
                                          partC, 77, (int)MT, 1024, 512, 2,
                                          nullptr, nullptr, nullptr);
  // q direct: aimg @ (Wi@Wq) + biasQ   (proj_img eliminated)
  gemm_one<<<dim3(784), 256, 0, stream>>>(aimg, wiwqT, biasQ, biasQ, nullptr, qBuf,
                                          nullptr, 1 << 30, (int)MI, 1024, 512, 2,
                                          nullptr, nullptr, nullptr);
  // kv: ptxt @ [Wk | Wv] + [bk | bv]
  gemm_one<<<dim3(616), 256, 0, stream>>>(ptxtB, wkt, bk, bv, nullptr, kvBuf,
                                          nullptr, 1 << 30, (int)MT, 512, 1024, 3,
                                          nullptr, nullptr, nullptr);

  attn_kernel<<<dim3(512), 256, 0, stream>>>(qBuf, kvBuf, attnB, wAll);
  meanw_kernel<<<dim3((BATCH * NP * TL + 255) / 256), 256, 0, stream>>>(wAll, oW);

  // attn output projection with fused avg column-sum into partA
  gemm_one<<<dim3(784), 256, 0, stream>>>(attnB, wot, bo, bo, oAttn, nullptr,
                                          partA, 196, (int)MI, 512, 512, 2,
                                          nullptr, nullptr, nullptr);

  avg_final<<<dim3(64), 256, 0, stream>>>(partA, partC, oAvg, oCls, normA, normC);
  score_kernel<<<dim3(64), 256, 0, stream>>>(normA, normC, oScore);
}